// Round 16
// baseline (342.662 us; speedup 1.0000x reference)
//
#include <hip/hip_runtime.h>
#include <math.h>
#include <type_traits>

#define NN 50000
#define EE 800000
#define IN_D 256
#define HH 128
#define OUT_D 64
#define DEPTH 3
#define BK 512
#define NBK 98    // ceil(NN/BK)

typedef unsigned short u16;
typedef __bf16  bf16x8 __attribute__((ext_vector_type(8)));
typedef short   short8 __attribute__((ext_vector_type(8)));
typedef float   f32x4  __attribute__((ext_vector_type(4)));

__device__ __forceinline__ u16 f2b(float f){
    unsigned u = __float_as_uint(f);
    u += 0x7fff + ((u>>16)&1);            // round-to-nearest-even
    return (u16)(u>>16);
}
__device__ __forceinline__ float b2f(u16 h){ return __uint_as_float(((unsigned)h)<<16); }

#define LOG2E 1.4426950408889634f
#if __has_builtin(__builtin_amdgcn_exp2f)
__device__ __forceinline__ float fexp2(float x){ return __builtin_amdgcn_exp2f(x); }
#else
__device__ __forceinline__ float fexp2(float x){ return exp2f(x); }
#endif
#if __has_builtin(__builtin_amdgcn_rcpf)
__device__ __forceinline__ float frcp(float x){ return __builtin_amdgcn_rcpf(x); }
#else
__device__ __forceinline__ float frcp(float x){ return 1.f/x; }
#endif
__device__ __forceinline__ float sigm(float x){ return frcp(1.f + fexp2(-x*LOG2E)); }
__device__ __forceinline__ float ftanh(float x){
    float ax = fabsf(x);
    float u = fexp2(ax * (-2.f*LOG2E));
    float r = (1.f - u) * frcp(1.f + u);
    return copysignf(r, x);
}

// ================= A-resident register GEMM (h0 / zel) =================
// LDS tile in MFMA-FRAGMENT order: frag(rt,ks) = 1KB, element slot = ksel*16+ml.
// k-loop reads are contiguous 1KB per wave (base + lane*16): conflict-free.
enum { EPI_BF=0, EPI_RELU=1, EPI_ZEL=2 };

template<int EPI, int WAVES, int CT, int K, typename TA>
__global__ __launch_bounds__(WAVES*64, 4) void rgemm_k(
    const TA* __restrict__ A1,
    const u16* __restrict__ Bp,
    const float* __restrict__ b1, const float* __restrict__ b2,
    void* __restrict__ Out, float* __restrict__ aux1, float* __restrict__ aux2,
    int Nrows)
{
    constexpr int TH = WAVES*64;
    constexpr int KS = K/32;
    constexpr int M  = WAVES*CT*16;
    __shared__ u16 As[64*K];
    __shared__ float elp[(EPI==EPI_ZEL)?64*WAVES:1];
    __shared__ float erp[(EPI==EPI_ZEL)?64*WAVES:1];

    const int tid = threadIdx.x;
    const int rb  = blockIdx.x*64;

    constexpr int CHUNKS = 64*K/(TH*8);
    #pragma unroll
    for (int c = 0; c < CHUNKS; ++c) {
        int cidx = tid + c*TH;
        int row = cidx & 63, kseg = cidx >> 6;
        int grow = rb + row; if (grow >= Nrows) grow = Nrows-1;
        short8 v;
        if constexpr (std::is_same<TA,float>::value) {
            const float* p = (const float*)A1 + (size_t)grow*K + kseg*8;
            float4 x0 = *(const float4*)p;
            float4 x1 = *(const float4*)(p+4);
            v[0]=(short)f2b(x0.x); v[1]=(short)f2b(x0.y); v[2]=(short)f2b(x0.z); v[3]=(short)f2b(x0.w);
            v[4]=(short)f2b(x1.x); v[5]=(short)f2b(x1.y); v[6]=(short)f2b(x1.z); v[7]=(short)f2b(x1.w);
        } else {
            v = *(const short8*)((const u16*)A1 + (size_t)grow*K + kseg*8);
        }
        int byte = ((row>>4)*KS + (kseg>>2))*1024 + ((kseg&3)*16 + (row&15))*16;
        *(short8*)((char*)As + byte) = v;
    }
    __syncthreads();

    const int lane = tid & 63, w = tid >> 6;
    const int ml = lane & 15, ksel = lane >> 4;
    f32x4 acc[4][CT] = {};
    #pragma unroll
    for (int ks = 0; ks < KS; ++ks) {
        bf16x8 a[4];
        #pragma unroll
        for (int rt = 0; rt < 4; ++rt)
            a[rt] = *(const bf16x8*)((const char*)As + (rt*KS + ks)*1024 + lane*16);
        #pragma unroll
        for (int j = 0; j < CT; ++j) {
            int ctg = j*WAVES + w;
            bf16x8 b = *(const bf16x8*)(Bp + (((size_t)(ctg*KS + ks))<<9) + lane*8);
            #pragma unroll
            for (int rt = 0; rt < 4; ++rt)
                acc[rt][j] = __builtin_amdgcn_mfma_f32_16x16x32_bf16(a[rt], b, acc[rt][j], 0,0,0);
        }
    }

    if constexpr (EPI==EPI_BF || EPI==EPI_RELU) {
        #pragma unroll
        for (int rt = 0; rt < 4; ++rt)
        #pragma unroll
        for (int r = 0; r < 4; ++r) {
            int row = rb + rt*16 + ksel*4 + r;
            if (row >= Nrows) continue;
            #pragma unroll
            for (int j = 0; j < CT; ++j) {
                int gc = (j*WAVES + w)*16 + ml;
                float vv = acc[rt][j][r] + b1[gc];
                if (EPI==EPI_BF) ((u16*)Out)[(size_t)row*M + gc]   = f2b(vv);
                else             ((float*)Out)[(size_t)row*M + gc] = fmaxf(vv, 0.f);
            }
        }
    } else {   // EPI_ZEL
        float pel[4][4] = {}, per[4][4] = {};
        #pragma unroll
        for (int j = 0; j < CT; ++j) {
            int gc = (j*WAVES + w)*16 + ml;
            float alc = b1[gc], arc = b2[gc];
            #pragma unroll
            for (int rt = 0; rt < 4; ++rt)
            #pragma unroll
            for (int r = 0; r < 4; ++r) {
                int row = rb + rt*16 + ksel*4 + r;
                float vv = acc[rt][j][r];
                if (row < Nrows) ((u16*)Out)[(size_t)row*HH + gc] = f2b(vv);
                pel[rt][r] = fmaf(vv, alc, pel[rt][r]);
                per[rt][r] = fmaf(vv, arc, per[rt][r]);
            }
        }
        #pragma unroll
        for (int msk = 1; msk < 16; msk <<= 1)
            #pragma unroll
            for (int rt = 0; rt < 4; ++rt)
            #pragma unroll
            for (int r = 0; r < 4; ++r) {
                pel[rt][r] += __shfl_xor(pel[rt][r], msk);
                per[rt][r] += __shfl_xor(per[rt][r], msk);
            }
        if (ml == 0) {
            #pragma unroll
            for (int rt = 0; rt < 4; ++rt)
            #pragma unroll
            for (int r = 0; r < 4; ++r) {
                int lr = rt*16 + ksel*4 + r;
                elp[lr*WAVES + w] = pel[rt][r];
                erp[lr*WAVES + w] = per[rt][r];
            }
        }
        __syncthreads();
        if (tid < 64) {
            int row = rb + tid;
            if (row < Nrows) {
                float s1 = 0.f, s2 = 0.f;
                #pragma unroll
                for (int wv = 0; wv < WAVES; ++wv) { s1 += elp[tid*WAVES+wv]; s2 += erp[tid*WAVES+wv]; }
                aux1[row] = s1; aux2[row] = s2;
            }
        }
    }
}

// ================= fused 3-layer depth kernel + out GEMM (32-row blocks) =================
// Same per-thread work as the 64-row version (acc[2][4][2] = 64 VGPR, 16 MFMA/ks)
// but 256-thread blocks: 4 independent barrier domains per CU instead of 2
// (VGPR ~84-110 -> 4 waves/SIMD -> 16 waves/CU either way; smaller blocks
// decouple barrier stalls). Fragment-order LDS (8 frags x 1KB per tile).
__global__ __launch_bounds__(256, 4) void depth_k(
    const u16* __restrict__ coll0, const u16* __restrict__ coll1, const u16* __restrict__ coll2,
    const u16* __restrict__ mu0,
    const u16* __restrict__ gateP, const u16* __restrict__ outP,
    const float* __restrict__ igb, const float* __restrict__ stb,
    const float* __restrict__ fgb, const float* __restrict__ ogb,
    const float* __restrict__ outb, float* __restrict__ Out,
    int Nrows)
{
    __shared__ u16 As[32*HH];   // 8 frags x 1KB
    __shared__ u16 Ms[32*HH];
    const int tid = threadIdx.x;
    const int rb  = blockIdx.x*32;
    const int lane = tid & 63, w = tid >> 6;   // w in 0..3
    const int ml = lane & 15, ksel = lane >> 4;

    // staging chunks, row-minor: cidx -> row = cidx&31, kseg = cidx>>5 (0..15)
    const int c0 = tid, c1 = tid + 256;
    const int row0 = c0 & 31, kg0 = c0 >> 5;
    const int row1 = c1 & 31, kg1 = c1 >> 5;
    int gr0 = rb + row0; if (gr0 >= Nrows) gr0 = Nrows-1;
    int gr1 = rb + row1; if (gr1 >= Nrows) gr1 = Nrows-1;
    const size_t off0 = (size_t)gr0*HH + kg0*8, off1 = (size_t)gr1*HH + kg1*8;
    const int dst0 = ((row0>>4)*4 + (kg0>>2))*1024 + ((kg0&3)*16 + (row0&15))*16;
    const int dst1 = ((row1>>4)*4 + (kg1>>2))*1024 + ((kg1&3)*16 + (row1&15))*16;

    // stage initial mu (= h0) and prefetch coll0
    *(short8*)((char*)Ms + dst0) = *(const short8*)(mu0 + off0);
    *(short8*)((char*)Ms + dst1) = *(const short8*)(mu0 + off1);
    short8 pf0 = *(const short8*)(coll0 + off0);
    short8 pf1 = *(const short8*)(coll0 + off1);

    float cc[2][2][4];   // [rt][j][r]
    #pragma unroll
    for (int i = 0; i < DEPTH; ++i) {
        __syncthreads();   // prev k-loop's As reads complete (no-op at i=0)
        *(short8*)((char*)As + dst0) = pf0;
        *(short8*)((char*)As + dst1) = pf1;
        if (i == 0) { pf0 = *(const short8*)(coll1 + off0); pf1 = *(const short8*)(coll1 + off1); }
        if (i == 1) { pf0 = *(const short8*)(coll2 + off0); pf1 = *(const short8*)(coll2 + off1); }
        __syncthreads();   // As ready; prev Ms writes visible

        f32x4 acc[2][4][2] = {};   // [rt][gate][j]
        #pragma unroll
        for (int ks = 0; ks < 8; ++ks) {
            const char* Sb = (ks < 4) ? (const char*)As : (const char*)Ms;
            bf16x8 a[2];
            #pragma unroll
            for (int rt = 0; rt < 2; ++rt)
                a[rt] = *(const bf16x8*)(Sb + (rt*4 + (ks&3))*1024 + lane*16);
            #pragma unroll
            for (int g = 0; g < 4; ++g)
            #pragma unroll
            for (int j = 0; j < 2; ++j) {
                bf16x8 b = *(const bf16x8*)(gateP + (size_t)i*131072 + ((g*8 + w*2 + j)*8 + ks)*512 + lane*8);
                #pragma unroll
                for (int rt = 0; rt < 2; ++rt)
                    acc[rt][g][j] = __builtin_amdgcn_mfma_f32_16x16x32_bf16(a[rt], b, acc[rt][g][j], 0,0,0);
            }
        }
        __syncthreads();   // ALL waves' Ms reads done before overwrite

        #pragma unroll
        for (int j = 0; j < 2; ++j) {
            int col = w*32 + j*16 + ml;
            float bi = igb[i*HH + col], bs = stb[i*HH + col];
            float bf_ = fgb[i*HH + col], bo = ogb[i*HH + col];
            const int slothi = (j*2 + (ml>>3))*16;   // khalf*16
            const int elem   = ml & 7;
            #pragma unroll
            for (int rt = 0; rt < 2; ++rt)
            #pragma unroll
            for (int r = 0; r < 4; ++r) {
                float ig = sigm (acc[rt][0][j][r] + bi);
                float st = ftanh(acc[rt][1][j][r] + bs);
                float fg = sigm (acc[rt][2][j][r] + bf_);
                float og = sigm (acc[rt][3][j][r] + bo);
                float P  = ig * st;
                float cn = (i == 0) ? P : fmaf(fg, cc[rt][j][r], P);
                cc[rt][j][r] = cn;
                float mun = og * ftanh(cn);
                int byte = (rt*4 + w)*1024 + (slothi + ksel*4 + r)*16 + elem*2;
                *(u16*)((char*)Ms + byte) = f2b(mun);
            }
        }
    }
    __syncthreads();   // final mu visible in Ms

    // ---- fused out GEMM: relu(mu @ outW + outb) -> d_out (4 waves, 1 col-chunk each) ----
    {
        f32x4 acc[2] = {};
        #pragma unroll
        for (int ks = 0; ks < 4; ++ks) {
            bf16x8 a[2];
            #pragma unroll
            for (int rt = 0; rt < 2; ++rt)
                a[rt] = *(const bf16x8*)((const char*)Ms + (rt*4 + ks)*1024 + lane*16);
            bf16x8 b = *(const bf16x8*)(outP + (size_t)((w*4 + ks)<<9) + lane*8);
            #pragma unroll
            for (int rt = 0; rt < 2; ++rt)
                acc[rt] = __builtin_amdgcn_mfma_f32_16x16x32_bf16(a[rt], b, acc[rt], 0,0,0);
        }
        int gc = w*16 + ml;
        float bb = outb[gc];
        #pragma unroll
        for (int rt = 0; rt < 2; ++rt)
        #pragma unroll
        for (int r = 0; r < 4; ++r) {
            int row = rb + rt*16 + ksel*4 + r;
            if (row < Nrows)
                Out[(size_t)row*OUT_D + gc] = fmaxf(acc[rt][r] + bb, 0.f);
        }
    }
}

// ================= weight pack =================
struct PK  { const float* s; u16* d; int K; int Mc; };
struct PKs { PK t[17]; };
__global__ __launch_bounds__(256) void pack_k(PKs ps){
    const PK t = ps.t[blockIdx.y];
    int o = blockIdx.x*256 + threadIdx.x;
    if (o >= t.K * t.Mc) return;
    int i = o & 7, lane = (o>>3) & 63, rst = o >> 9;
    int KS = t.K >> 5;
    int ks = rst % KS, ct = rst / KS;
    int col = ct*16 + (lane & 15);
    int k   = ks*32 + (lane>>4)*8 + i;
    t.d[o] = f2b(t.s[(size_t)k*t.Mc + col]);
}

// ================= bucketized CSR build =================
__global__ __launch_bounds__(256) void binh_k(const int* __restrict__ dst, int* __restrict__ bcnt){
    __shared__ int h[NBK];
    int t = threadIdx.x;
    if (t < NBK) h[t] = 0;
    __syncthreads();
    int base = blockIdx.x*4096;
    #pragma unroll
    for (int c = 0; c < 16; ++c){ int e = base + c*256 + t; if (e < EE) atomicAdd(&h[dst[e]>>9], 1); }
    __syncthreads();
    if (t < NBK && h[t]) atomicAdd(&bcnt[t], h[t]);
}
__global__ __launch_bounds__(128) void bscan_k(const int* __restrict__ bcnt,
                                               int* __restrict__ bbase, int* __restrict__ gcur){
    __shared__ int s[128];
    int t = threadIdx.x;
    int v = (t < NBK) ? bcnt[t] : 0;
    s[t] = v; __syncthreads();
    for (int off=1; off<128; off<<=1){ int x = (t>=off)? s[t-off] : 0; __syncthreads(); s[t] += x; __syncthreads(); }
    if (t < NBK){ bbase[t] = s[t]-v; gcur[t] = s[t]-v; }
}
__global__ __launch_bounds__(256) void binsc_k(const int* __restrict__ dst, const int* __restrict__ src,
                                               int* __restrict__ gcur, unsigned* __restrict__ staged){
    __shared__ int h[NBK], bb[NBK], lc[NBK];
    int t = threadIdx.x;
    if (t < NBK){ h[t]=0; lc[t]=0; }
    __syncthreads();
    int base = blockIdx.x*4096;
    int d[16], s[16];
    #pragma unroll
    for (int c = 0; c < 16; ++c){
        int e = base + c*256 + t; d[c] = -1;
        if (e < EE){ d[c] = dst[e]; s[c] = src[e]; atomicAdd(&h[d[c]>>9], 1); }
    }
    __syncthreads();
    if (t < NBK && h[t]) bb[t] = atomicAdd(&gcur[t], h[t]);
    __syncthreads();
    #pragma unroll
    for (int c = 0; c < 16; ++c) if (d[c] >= 0){
        int b = d[c]>>9;
        int r = atomicAdd(&lc[b], 1);
        staged[bb[b] + r] = ((unsigned)(d[c] & 511) << 16) | (unsigned)s[c];
    }
}
__global__ __launch_bounds__(BK) void build_k(const int* __restrict__ bcnt, const int* __restrict__ bbase,
                                              const unsigned* __restrict__ staged,
                                              int* __restrict__ rp, int* __restrict__ deg, u16* __restrict__ srcs){
    __shared__ int soff[BK], cur[BK];
    int t = threadIdx.x, bk = blockIdx.x;
    int n0 = bk*BK;
    soff[t] = 0; cur[t] = 0;
    __syncthreads();
    int cb = bcnt[bk], eb = bbase[bk];
    for (int j = t; j < cb; j += BK) atomicAdd(&soff[staged[eb+j]>>16], 1);
    __syncthreads();
    int d0 = soff[t];
    for (int off=1; off<BK; off<<=1){ int x = (t>=off)? soff[t-off] : 0; __syncthreads(); soff[t] += x; __syncthreads(); }
    int ex = soff[t] - d0;
    __syncthreads();
    soff[t] = ex;
    int n = n0 + t;
    if (n < NN){ deg[n] = d0; rp[n] = eb + ex; }
    __syncthreads();
    for (int j = t; j < cb; j += BK){
        unsigned p = staged[eb+j];
        int l = p >> 16;
        int r = atomicAdd(&cur[l], 1);
        srcs[eb + soff[l] + r] = (u16)(p & 0xffff);
    }
}

// ================= fused attention-softmax + gather =================
// Wave-uniform gather trip count so all __shfl sources are active lanes (R8
// lesson). 4 edges per iteration: 4 independent gathers in flight per wave.
// OOB slots: weight 0 (a_reg=0 for lane>=cnt), gather z[0] harmlessly.
__global__ __launch_bounds__(256) void gat_k(
    const u16* __restrict__ z, const float* __restrict__ el, const float* __restrict__ er,
    const u16* __restrict__ srcs, const int* __restrict__ rp, const int* __restrict__ deg,
    const float* __restrict__ bias, u16* __restrict__ hout)
{
    int n = blockIdx.x*4 + (threadIdx.x>>6);
    if (n >= NN) return;
    int lane = threadIdx.x & 63;
    int start = rp[n], cnt = deg[n];
    float ern = er[n];
    const int slot = lane >> 4;
    const int ch   = (lane & 15) * 8;
    float acc[8] = {};

    if (cnt <= 64) {
        float v = -1e30f; int s_reg = 0;
        if (lane < cnt) {
            s_reg = srcs[start + lane];
            float tv = el[s_reg] + ern;
            v = tv >= 0.f ? tv : 0.2f*tv;
        }
        float m = v;
        #pragma unroll
        for (int off=1; off<64; off<<=1) m = fmaxf(m, __shfl_xor(m, off));
        float a = (lane < cnt) ? fexp2((v - m)*LOG2E) : 0.f;
        float ss = a;
        #pragma unroll
        for (int off=1; off<64; off<<=1) ss += __shfl_xor(ss, off);
        float a_reg = a * frcp(fmaxf(ss, 1e-16f));

        const int cntp = (cnt + 15) & ~15;   // uniform across the wave
        for (int i = slot; i < cntp; i += 16) {
            float w0 = __shfl(a_reg, i),    w1 = __shfl(a_reg, i+4);
            float w2 = __shfl(a_reg, i+8),  w3 = __shfl(a_reg, i+12);
            int   s0 = __shfl(s_reg, i),    s1 = __shfl(s_reg, i+4);
            int   s2 = __shfl(s_reg, i+8),  s3 = __shfl(s_reg, i+12);
            short8 v0 = *(const short8*)(z + (size_t)s0*HH + ch);
            short8 v1 = *(const short8*)(z + (size_t)s1*HH + ch);
            short8 v2 = *(const short8*)(z + (size_t)s2*HH + ch);
            short8 v3 = *(const short8*)(z + (size_t)s3*HH + ch);
            #pragma unroll
            for (int j=0;j<8;j++)
                acc[j] = fmaf(w3, b2f((u16)v3[j]),
                         fmaf(w2, b2f((u16)v2[j]),
                         fmaf(w1, b2f((u16)v1[j]),
                         fmaf(w0, b2f((u16)v0[j]), acc[j]))));
        }
    } else {   // generic fallback (degree > 64); no shfl in divergent loops
        float m = -1e30f;
        for (int i=lane; i<cnt; i+=64){ float tv = el[srcs[start+i]] + ern; tv = tv>=0.f?tv:0.2f*tv; m = fmaxf(m, tv); }
        #pragma unroll
        for (int off=1; off<64; off<<=1) m = fmaxf(m, __shfl_xor(m, off));
        float ss = 0.f;
        for (int i=lane; i<cnt; i+=64){ float tv = el[srcs[start+i]] + ern; tv = tv>=0.f?tv:0.2f*tv; ss += fexp2((tv-m)*LOG2E); }
        #pragma unroll
        for (int off=1; off<64; off<<=1) ss += __shfl_xor(ss, off);
        float inv = frcp(fmaxf(ss, 1e-16f));
        for (int i=slot; i<cnt; i+=4) {
            int sn = srcs[start+i];
            float tv = el[sn] + ern; tv = tv>=0.f?tv:0.2f*tv;
            float w0 = fexp2((tv-m)*LOG2E) * inv;
            short8 v0 = *(const short8*)(z + (size_t)sn*HH + ch);
            #pragma unroll
            for (int j=0;j<8;j++) acc[j] = fmaf(w0, b2f((u16)v0[j]), acc[j]);
        }
    }
    #pragma unroll
    for (int j=0;j<8;j++){ acc[j] += __shfl_xor(acc[j],16); acc[j] += __shfl_xor(acc[j],32); }
    if (slot == 0) {
        short8 o8;
        #pragma unroll
        for (int j=0;j<8;j++) o8[j] = (short)f2b(ftanh(acc[j] + bias[ch+j]));
        *(short8*)(hout + (size_t)n*HH + ch) = o8;
    }
}

extern "C" void kernel_launch(void* const* d_in, const int* in_sizes, int n_in,
                              void* d_out, int out_size, void* d_ws, size_t ws_size,
                              hipStream_t stream)
{
    const float* x    = (const float*)d_in[0];
    const int*   src  = (const int*)d_in[1];
    const int*   dst  = (const int*)d_in[2];
    const float* wxW  = (const float*)d_in[3];
    const float* wxb  = (const float*)d_in[4];
    const float* gatW = (const float*)d_in[5];
    const float* gatb = (const float*)d_in[6];
    const float* attl = (const float*)d_in[7];
    const float* attr = (const float*)d_in[8];
    const float* igW  = (const float*)d_in[9];
    const float* igb  = (const float*)d_in[10];
    const float* fgW  = (const float*)d_in[11];
    const float* fgb  = (const float*)d_in[12];
    const float* ogW  = (const float*)d_in[13];
    const float* ogb  = (const float*)d_in[14];
    const float* stW  = (const float*)d_in[15];
    const float* stb  = (const float*)d_in[16];
    const float* outW = (const float*)d_in[17];
    const float* outb = (const float*)d_in[18];

    char* w = (char*)d_ws;
    auto alloc = [&](size_t bytes)->char* { char* p = w; w += (bytes + 255) & ~(size_t)255; return p; };
    const size_t NH = (size_t)NN * HH;
    u16*      muB    = (u16*)alloc(NH*2);
    u16*      zB     = (u16*)alloc(NH*2);
    u16*      coll0  = (u16*)alloc(NH*2);
    u16*      coll1  = (u16*)alloc(NH*2);
    u16*      coll2  = (u16*)alloc(NH*2);
    float*    el     = (float*)alloc((size_t)NN*4);
    float*    er     = (float*)alloc((size_t)NN*4);
    unsigned* staged = (unsigned*)alloc((size_t)EE*4);
    u16*      srcs   = (u16*)alloc((size_t)EE*2);
    int*      deg    = (int*)alloc((size_t)NN*4);
    int*      rp     = (int*)alloc((size_t)NN*4);
    int*      bcnt   = (int*)alloc(128*4);
    int*      bbase  = (int*)alloc(128*4);
    int*      gcur   = (int*)alloc(128*4);
    u16*      bpool  = (u16*)alloc(483328*2);
    u16* wxP   = bpool;
    u16* gatP  = bpool + 32768;
    u16* gateP = bpool + 81920;
    u16* outP  = bpool + 475136;
    u16* coll[3] = {coll0, coll1, coll2};

    // ---- pack weights into MFMA fragment order ----
    PKs ps;
    ps.t[0] = {wxW, wxP, IN_D, HH};
    for (int i=0;i<3;i++) ps.t[1+i]  = {gatW + (size_t)i*HH*HH,   gatP  + i*16384,           HH,   HH};
    for (int i=0;i<3;i++) ps.t[4+i]  = {igW  + (size_t)i*2*HH*HH, gateP + i*131072,          2*HH, HH};
    for (int i=0;i<3;i++) ps.t[7+i]  = {stW  + (size_t)i*2*HH*HH, gateP + i*131072 + 32768,  2*HH, HH};
    for (int i=0;i<3;i++) ps.t[10+i] = {fgW  + (size_t)i*2*HH*HH, gateP + i*131072 + 65536,  2*HH, HH};
    for (int i=0;i<3;i++) ps.t[13+i] = {ogW  + (size_t)i*2*HH*HH, gateP + i*131072 + 98304,  2*HH, HH};
    ps.t[16] = {outW, outP, HH, OUT_D};
    pack_k<<<dim3(128,17), 256, 0, stream>>>(ps);

    // ---- bucketized CSR build ----
    hipMemsetAsync(bcnt, 0, 128*4, stream);
    const int gE = (EE + 4095) / 4096;   // 196
    binh_k <<<gE, 256, 0, stream>>>(dst, bcnt);
    bscan_k<<<1, 128, 0, stream>>>(bcnt, bbase, gcur);
    binsc_k<<<gE, 256, 0, stream>>>(dst, src, gcur, staged);
    build_k<<<NBK, BK, 0, stream>>>(bcnt, bbase, staged, rp, deg, srcs);

    const int gN  = (NN + 63) / 64;   // 782
    const int gN2 = (NN + 31) / 32;   // 1563
    const int gA  = (NN + 3) / 4;     // 12500

    // ---- h0 = x @ wxW + wxb -> muB ----
    rgemm_k<EPI_BF,4,2,IN_D,float><<<gN, 256, 0, stream>>>(
        x, wxP, wxb, nullptr, muB, nullptr, nullptr, NN);

    // ---- GAT layers ----
    const u16* hin = muB;
    for (int i = 0; i < DEPTH; ++i) {
        rgemm_k<EPI_ZEL,4,2,HH,u16><<<gN, 256, 0, stream>>>(
            hin, gatP + i*16384, attl + i*HH, attr + i*HH, zB, el, er, NN);
        gat_k<<<gA, 256, 0, stream>>>(zB, el, er, srcs, rp, deg, gatb + i*HH, coll[i]);
        hin = coll[i];
    }

    // ---- depth + out: single fused kernel (32-row blocks) ----
    depth_k<<<gN2, 256, 0, stream>>>(coll0, coll1, coll2, muB, gateP, outP,
                                     igb, stb, fgb, ogb, outb, (float*)d_out, NN);
}

// Round 17
// 302.468 us; speedup vs baseline: 1.1329x; 1.1329x over previous
//
#include <hip/hip_runtime.h>
#include <math.h>
#include <type_traits>

#define NN 50000
#define EE 800000
#define IN_D 256
#define HH 128
#define OUT_D 64
#define DEPTH 3
#define BK 512
#define NBK 98    // ceil(NN/BK)

typedef unsigned short u16;
typedef __bf16  bf16x8 __attribute__((ext_vector_type(8)));
typedef short   short8 __attribute__((ext_vector_type(8)));
typedef float   f32x4  __attribute__((ext_vector_type(4)));

__device__ __forceinline__ u16 f2b(float f){
    unsigned u = __float_as_uint(f);
    u += 0x7fff + ((u>>16)&1);            // round-to-nearest-even
    return (u16)(u>>16);
}
__device__ __forceinline__ float b2f(u16 h){ return __uint_as_float(((unsigned)h)<<16); }

#define LOG2E 1.4426950408889634f
#if __has_builtin(__builtin_amdgcn_exp2f)
__device__ __forceinline__ float fexp2(float x){ return __builtin_amdgcn_exp2f(x); }
#else
__device__ __forceinline__ float fexp2(float x){ return exp2f(x); }
#endif
#if __has_builtin(__builtin_amdgcn_rcpf)
__device__ __forceinline__ float frcp(float x){ return __builtin_amdgcn_rcpf(x); }
#else
__device__ __forceinline__ float frcp(float x){ return 1.f/x; }
#endif
__device__ __forceinline__ float sigm(float x){ return frcp(1.f + fexp2(-x*LOG2E)); }
__device__ __forceinline__ float ftanh(float x){
    float ax = fabsf(x);
    float u = fexp2(ax * (-2.f*LOG2E));
    float r = (1.f - u) * frcp(1.f + u);
    return copysignf(r, x);
}

// ================= A-resident register GEMM (h0 / zel) =================
// LDS tile in MFMA-FRAGMENT order: frag(rt,ks) = 1KB, element slot = ksel*16+ml.
// k-loop reads are contiguous 1KB per wave (base + lane*16): conflict-free.
enum { EPI_BF=0, EPI_RELU=1, EPI_ZEL=2 };

template<int EPI, int WAVES, int CT, int K, typename TA>
__global__ __launch_bounds__(WAVES*64, 4) void rgemm_k(
    const TA* __restrict__ A1,
    const u16* __restrict__ Bp,
    const float* __restrict__ b1, const float* __restrict__ b2,
    void* __restrict__ Out, float* __restrict__ aux1, float* __restrict__ aux2,
    int Nrows)
{
    constexpr int TH = WAVES*64;
    constexpr int KS = K/32;
    constexpr int M  = WAVES*CT*16;
    __shared__ u16 As[64*K];
    __shared__ float elp[(EPI==EPI_ZEL)?64*WAVES:1];
    __shared__ float erp[(EPI==EPI_ZEL)?64*WAVES:1];

    const int tid = threadIdx.x;
    const int rb  = blockIdx.x*64;

    constexpr int CHUNKS = 64*K/(TH*8);
    #pragma unroll
    for (int c = 0; c < CHUNKS; ++c) {
        int cidx = tid + c*TH;
        int row = cidx & 63, kseg = cidx >> 6;
        int grow = rb + row; if (grow >= Nrows) grow = Nrows-1;
        short8 v;
        if constexpr (std::is_same<TA,float>::value) {
            const float* p = (const float*)A1 + (size_t)grow*K + kseg*8;
            float4 x0 = *(const float4*)p;
            float4 x1 = *(const float4*)(p+4);
            v[0]=(short)f2b(x0.x); v[1]=(short)f2b(x0.y); v[2]=(short)f2b(x0.z); v[3]=(short)f2b(x0.w);
            v[4]=(short)f2b(x1.x); v[5]=(short)f2b(x1.y); v[6]=(short)f2b(x1.z); v[7]=(short)f2b(x1.w);
        } else {
            v = *(const short8*)((const u16*)A1 + (size_t)grow*K + kseg*8);
        }
        int byte = ((row>>4)*KS + (kseg>>2))*1024 + ((kseg&3)*16 + (row&15))*16;
        *(short8*)((char*)As + byte) = v;
    }
    __syncthreads();

    const int lane = tid & 63, w = tid >> 6;
    const int ml = lane & 15, ksel = lane >> 4;
    f32x4 acc[4][CT] = {};
    #pragma unroll
    for (int ks = 0; ks < KS; ++ks) {
        bf16x8 a[4];
        #pragma unroll
        for (int rt = 0; rt < 4; ++rt)
            a[rt] = *(const bf16x8*)((const char*)As + (rt*KS + ks)*1024 + lane*16);
        #pragma unroll
        for (int j = 0; j < CT; ++j) {
            int ctg = j*WAVES + w;
            bf16x8 b = *(const bf16x8*)(Bp + (((size_t)(ctg*KS + ks))<<9) + lane*8);
            #pragma unroll
            for (int rt = 0; rt < 4; ++rt)
                acc[rt][j] = __builtin_amdgcn_mfma_f32_16x16x32_bf16(a[rt], b, acc[rt][j], 0,0,0);
        }
    }

    if constexpr (EPI==EPI_BF || EPI==EPI_RELU) {
        #pragma unroll
        for (int rt = 0; rt < 4; ++rt)
        #pragma unroll
        for (int r = 0; r < 4; ++r) {
            int row = rb + rt*16 + ksel*4 + r;
            if (row >= Nrows) continue;
            #pragma unroll
            for (int j = 0; j < CT; ++j) {
                int gc = (j*WAVES + w)*16 + ml;
                float vv = acc[rt][j][r] + b1[gc];
                if (EPI==EPI_BF) ((u16*)Out)[(size_t)row*M + gc]   = f2b(vv);
                else             ((float*)Out)[(size_t)row*M + gc] = fmaxf(vv, 0.f);
            }
        }
    } else {   // EPI_ZEL
        float pel[4][4] = {}, per[4][4] = {};
        #pragma unroll
        for (int j = 0; j < CT; ++j) {
            int gc = (j*WAVES + w)*16 + ml;
            float alc = b1[gc], arc = b2[gc];
            #pragma unroll
            for (int rt = 0; rt < 4; ++rt)
            #pragma unroll
            for (int r = 0; r < 4; ++r) {
                int row = rb + rt*16 + ksel*4 + r;
                float vv = acc[rt][j][r];
                if (row < Nrows) ((u16*)Out)[(size_t)row*HH + gc] = f2b(vv);
                pel[rt][r] = fmaf(vv, alc, pel[rt][r]);
                per[rt][r] = fmaf(vv, arc, per[rt][r]);
            }
        }
        #pragma unroll
        for (int msk = 1; msk < 16; msk <<= 1)
            #pragma unroll
            for (int rt = 0; rt < 4; ++rt)
            #pragma unroll
            for (int r = 0; r < 4; ++r) {
                pel[rt][r] += __shfl_xor(pel[rt][r], msk);
                per[rt][r] += __shfl_xor(per[rt][r], msk);
            }
        if (ml == 0) {
            #pragma unroll
            for (int rt = 0; rt < 4; ++rt)
            #pragma unroll
            for (int r = 0; r < 4; ++r) {
                int lr = rt*16 + ksel*4 + r;
                elp[lr*WAVES + w] = pel[rt][r];
                erp[lr*WAVES + w] = per[rt][r];
            }
        }
        __syncthreads();
        if (tid < 64) {
            int row = rb + tid;
            if (row < Nrows) {
                float s1 = 0.f, s2 = 0.f;
                #pragma unroll
                for (int wv = 0; wv < WAVES; ++wv) { s1 += elp[tid*WAVES+wv]; s2 += erp[tid*WAVES+wv]; }
                aux1[row] = s1; aux2[row] = s2;
            }
        }
    }
}

// ================= fused 3-layer depth kernel + out GEMM (R13-best) =================
// Fragment-order LDS (conflict-free k-loop reads). 3 barriers/layer + explicit
// bc/bn B double-buffer -- measured best (93us). R14 2-barrier (+14us) and
// R16 32-row blocks (+43us, spilled) both regressed; this structure is the
// measured plateau. coll prefetched one layer ahead via pf regs.
__global__ __launch_bounds__(512, 3) void depth_k(
    const u16* __restrict__ coll0, const u16* __restrict__ coll1, const u16* __restrict__ coll2,
    const u16* __restrict__ mu0,
    const u16* __restrict__ gateP, const u16* __restrict__ outP,
    const float* __restrict__ igb, const float* __restrict__ stb,
    const float* __restrict__ fgb, const float* __restrict__ ogb,
    const float* __restrict__ outb, float* __restrict__ Out,
    int Nrows)
{
    __shared__ u16 As[64*HH];   // 16 frags x 1KB
    __shared__ u16 Ms[64*HH];
    const int tid = threadIdx.x;
    const int rb  = blockIdx.x*64;
    const int lane = tid & 63, w = tid >> 6;
    const int ml = lane & 15, ksel = lane >> 4;
    const int gcg = w*16 + ml;

    // staging chunks, row-minor: cidx -> row = cidx&63, kseg = cidx>>6 (0..15)
    const int c0 = tid, c1 = tid + 512;
    const int row0 = c0 & 63, kg0 = c0 >> 6;
    const int row1 = c1 & 63, kg1 = c1 >> 6;
    int gr0 = rb + row0; if (gr0 >= Nrows) gr0 = Nrows-1;
    int gr1 = rb + row1; if (gr1 >= Nrows) gr1 = Nrows-1;
    const size_t off0 = (size_t)gr0*HH + kg0*8, off1 = (size_t)gr1*HH + kg1*8;
    const int dst0 = ((row0>>4)*4 + (kg0>>2))*1024 + ((kg0&3)*16 + (row0&15))*16;
    const int dst1 = ((row1>>4)*4 + (kg1>>2))*1024 + ((kg1&3)*16 + (row1&15))*16;

    // stage initial mu (= h0) and prefetch coll0
    *(short8*)((char*)Ms + dst0) = *(const short8*)(mu0 + off0);
    *(short8*)((char*)Ms + dst1) = *(const short8*)(mu0 + off1);
    short8 pf0 = *(const short8*)(coll0 + off0);
    short8 pf1 = *(const short8*)(coll0 + off1);

    float cc[4][4];
    #pragma unroll
    for (int i = 0; i < DEPTH; ++i) {
        __syncthreads();   // prev k-loop's As reads complete (no-op at i=0)
        *(short8*)((char*)As + dst0) = pf0;
        *(short8*)((char*)As + dst1) = pf1;
        if (i == 0) { pf0 = *(const short8*)(coll1 + off0); pf1 = *(const short8*)(coll1 + off1); }
        if (i == 1) { pf0 = *(const short8*)(coll2 + off0); pf1 = *(const short8*)(coll2 + off1); }
        __syncthreads();   // As ready; prev Ms writes visible

        f32x4 acc[4][4] = {};   // [rt][gate]
        bf16x8 bc[4];
        #pragma unroll
        for (int g = 0; g < 4; ++g)
            bc[g] = *(const bf16x8*)(gateP + (size_t)i*131072 + (g*8 + w)*4096 + lane*8);
        #pragma unroll
        for (int ks = 0; ks < 8; ++ks) {
            bf16x8 bn[4];
            if (ks < 7) {
                #pragma unroll
                for (int g = 0; g < 4; ++g)
                    bn[g] = *(const bf16x8*)(gateP + (size_t)i*131072 + (g*8 + w)*4096 + (ks+1)*512 + lane*8);
            }
            const char* Sb = (ks < 4) ? (const char*)As : (const char*)Ms;
            bf16x8 a[4];
            #pragma unroll
            for (int rt = 0; rt < 4; ++rt)
                a[rt] = *(const bf16x8*)(Sb + (rt*4 + (ks&3))*1024 + lane*16);
            #pragma unroll
            for (int g = 0; g < 4; ++g)
                #pragma unroll
                for (int rt = 0; rt < 4; ++rt)
                    acc[rt][g] = __builtin_amdgcn_mfma_f32_16x16x32_bf16(a[rt], bc[g], acc[rt][g], 0,0,0);
            if (ks < 7) {
                #pragma unroll
                for (int g = 0; g < 4; ++g) bc[g] = bn[g];
            }
        }
        __syncthreads();   // ALL waves' Ms reads done before overwrite

        float bi = igb[i*HH + gcg], bs = stb[i*HH + gcg];
        float bf_ = fgb[i*HH + gcg], bo = ogb[i*HH + gcg];
        const int fks  = gcg >> 5;          // Ms frag column-group
        const int shi  = (gcg >> 3) & 3;    // slot high bits from column
        const int elem = gcg & 7;
        #pragma unroll
        for (int rt = 0; rt < 4; ++rt)
        #pragma unroll
        for (int r = 0; r < 4; ++r) {
            float ig = sigm (acc[rt][0][r] + bi);
            float st = ftanh(acc[rt][1][r] + bs);
            float fg = sigm (acc[rt][2][r] + bf_);
            float og = sigm (acc[rt][3][r] + bo);
            float P  = ig * st;
            float cn = (i == 0) ? P : fmaf(fg, cc[rt][r], P);
            cc[rt][r] = cn;
            float mun = og * ftanh(cn);
            int byte = (rt*4 + fks)*1024 + (shi*16 + (ksel*4 + r))*16 + elem*2;
            *(u16*)((char*)Ms + byte) = f2b(mun);
        }
    }
    __syncthreads();   // final mu visible in Ms

    // ---- fused out GEMM: relu(mu @ outW + outb) -> d_out (all 8 waves) ----
    {
        const int ct = w & 3;          // col tile (OUT_D = 4 x 16)
        const int rh = (w >> 2) * 2;   // row-tile base
        f32x4 acc[2] = {};
        #pragma unroll
        for (int ks = 0; ks < 4; ++ks) {
            bf16x8 a[2];
            #pragma unroll
            for (int q = 0; q < 2; ++q)
                a[q] = *(const bf16x8*)((const char*)Ms + ((rh+q)*4 + ks)*1024 + lane*16);
            bf16x8 b = *(const bf16x8*)(outP + (size_t)((ct*4 + ks)<<9) + lane*8);
            #pragma unroll
            for (int q = 0; q < 2; ++q)
                acc[q] = __builtin_amdgcn_mfma_f32_16x16x32_bf16(a[q], b, acc[q], 0,0,0);
        }
        int gc = ct*16 + ml;
        float bb = outb[gc];
        #pragma unroll
        for (int q = 0; q < 2; ++q)
        #pragma unroll
        for (int r = 0; r < 4; ++r) {
            int row = rb + (rh + q)*16 + ksel*4 + r;
            if (row < Nrows)
                Out[(size_t)row*OUT_D + gc] = fmaxf(acc[q][r] + bb, 0.f);
        }
    }
}

// ================= weight pack =================
struct PK  { const float* s; u16* d; int K; int Mc; };
struct PKs { PK t[17]; };
__global__ __launch_bounds__(256) void pack_k(PKs ps){
    const PK t = ps.t[blockIdx.y];
    int o = blockIdx.x*256 + threadIdx.x;
    if (o >= t.K * t.Mc) return;
    int i = o & 7, lane = (o>>3) & 63, rst = o >> 9;
    int KS = t.K >> 5;
    int ks = rst % KS, ct = rst / KS;
    int col = ct*16 + (lane & 15);
    int k   = ks*32 + (lane>>4)*8 + i;
    t.d[o] = f2b(t.s[(size_t)k*t.Mc + col]);
}

// ================= bucketized CSR build =================
__global__ __launch_bounds__(256) void binh_k(const int* __restrict__ dst, int* __restrict__ bcnt){
    __shared__ int h[NBK];
    int t = threadIdx.x;
    if (t < NBK) h[t] = 0;
    __syncthreads();
    int base = blockIdx.x*4096;
    #pragma unroll
    for (int c = 0; c < 16; ++c){ int e = base + c*256 + t; if (e < EE) atomicAdd(&h[dst[e]>>9], 1); }
    __syncthreads();
    if (t < NBK && h[t]) atomicAdd(&bcnt[t], h[t]);
}
__global__ __launch_bounds__(128) void bscan_k(const int* __restrict__ bcnt,
                                               int* __restrict__ bbase, int* __restrict__ gcur){
    __shared__ int s[128];
    int t = threadIdx.x;
    int v = (t < NBK) ? bcnt[t] : 0;
    s[t] = v; __syncthreads();
    for (int off=1; off<128; off<<=1){ int x = (t>=off)? s[t-off] : 0; __syncthreads(); s[t] += x; __syncthreads(); }
    if (t < NBK){ bbase[t] = s[t]-v; gcur[t] = s[t]-v; }
}
__global__ __launch_bounds__(256) void binsc_k(const int* __restrict__ dst, const int* __restrict__ src,
                                               int* __restrict__ gcur, unsigned* __restrict__ staged){
    __shared__ int h[NBK], bb[NBK], lc[NBK];
    int t = threadIdx.x;
    if (t < NBK){ h[t]=0; lc[t]=0; }
    __syncthreads();
    int base = blockIdx.x*4096;
    int d[16], s[16];
    #pragma unroll
    for (int c = 0; c < 16; ++c){
        int e = base + c*256 + t; d[c] = -1;
        if (e < EE){ d[c] = dst[e]; s[c] = src[e]; atomicAdd(&h[d[c]>>9], 1); }
    }
    __syncthreads();
    if (t < NBK && h[t]) bb[t] = atomicAdd(&gcur[t], h[t]);
    __syncthreads();
    #pragma unroll
    for (int c = 0; c < 16; ++c) if (d[c] >= 0){
        int b = d[c]>>9;
        int r = atomicAdd(&lc[b], 1);
        staged[bb[b] + r] = ((unsigned)(d[c] & 511) << 16) | (unsigned)s[c];
    }
}
__global__ __launch_bounds__(BK) void build_k(const int* __restrict__ bcnt, const int* __restrict__ bbase,
                                              const unsigned* __restrict__ staged,
                                              int* __restrict__ rp, int* __restrict__ deg, u16* __restrict__ srcs){
    __shared__ int soff[BK], cur[BK];
    int t = threadIdx.x, bk = blockIdx.x;
    int n0 = bk*BK;
    soff[t] = 0; cur[t] = 0;
    __syncthreads();
    int cb = bcnt[bk], eb = bbase[bk];
    for (int j = t; j < cb; j += BK) atomicAdd(&soff[staged[eb+j]>>16], 1);
    __syncthreads();
    int d0 = soff[t];
    for (int off=1; off<BK; off<<=1){ int x = (t>=off)? soff[t-off] : 0; __syncthreads(); soff[t] += x; __syncthreads(); }
    int ex = soff[t] - d0;
    __syncthreads();
    soff[t] = ex;
    int n = n0 + t;
    if (n < NN){ deg[n] = d0; rp[n] = eb + ex; }
    __syncthreads();
    for (int j = t; j < cb; j += BK){
        unsigned p = staged[eb+j];
        int l = p >> 16;
        int r = atomicAdd(&cur[l], 1);
        srcs[eb + soff[l] + r] = (u16)(p & 0xffff);
    }
}

// ================= fused attention-softmax + gather =================
// Wave-uniform gather trip count so all __shfl sources are active lanes (R8
// lesson). 4 edges per iteration: 4 independent gathers in flight per wave.
// OOB slots: weight 0 (a_reg=0 for lane>=cnt), gather z[0] harmlessly.
__global__ __launch_bounds__(256) void gat_k(
    const u16* __restrict__ z, const float* __restrict__ el, const float* __restrict__ er,
    const u16* __restrict__ srcs, const int* __restrict__ rp, const int* __restrict__ deg,
    const float* __restrict__ bias, u16* __restrict__ hout)
{
    int n = blockIdx.x*4 + (threadIdx.x>>6);
    if (n >= NN) return;
    int lane = threadIdx.x & 63;
    int start = rp[n], cnt = deg[n];
    float ern = er[n];
    const int slot = lane >> 4;
    const int ch   = (lane & 15) * 8;
    float acc[8] = {};

    if (cnt <= 64) {
        float v = -1e30f; int s_reg = 0;
        if (lane < cnt) {
            s_reg = srcs[start + lane];
            float tv = el[s_reg] + ern;
            v = tv >= 0.f ? tv : 0.2f*tv;
        }
        float m = v;
        #pragma unroll
        for (int off=1; off<64; off<<=1) m = fmaxf(m, __shfl_xor(m, off));
        float a = (lane < cnt) ? fexp2((v - m)*LOG2E) : 0.f;
        float ss = a;
        #pragma unroll
        for (int off=1; off<64; off<<=1) ss += __shfl_xor(ss, off);
        float a_reg = a * frcp(fmaxf(ss, 1e-16f));

        const int cntp = (cnt + 15) & ~15;   // uniform across the wave
        for (int i = slot; i < cntp; i += 16) {
            float w0 = __shfl(a_reg, i),    w1 = __shfl(a_reg, i+4);
            float w2 = __shfl(a_reg, i+8),  w3 = __shfl(a_reg, i+12);
            int   s0 = __shfl(s_reg, i),    s1 = __shfl(s_reg, i+4);
            int   s2 = __shfl(s_reg, i+8),  s3 = __shfl(s_reg, i+12);
            short8 v0 = *(const short8*)(z + (size_t)s0*HH + ch);
            short8 v1 = *(const short8*)(z + (size_t)s1*HH + ch);
            short8 v2 = *(const short8*)(z + (size_t)s2*HH + ch);
            short8 v3 = *(const short8*)(z + (size_t)s3*HH + ch);
            #pragma unroll
            for (int j=0;j<8;j++)
                acc[j] = fmaf(w3, b2f((u16)v3[j]),
                         fmaf(w2, b2f((u16)v2[j]),
                         fmaf(w1, b2f((u16)v1[j]),
                         fmaf(w0, b2f((u16)v0[j]), acc[j]))));
        }
    } else {   // generic fallback (degree > 64); no shfl in divergent loops
        float m = -1e30f;
        for (int i=lane; i<cnt; i+=64){ float tv = el[srcs[start+i]] + ern; tv = tv>=0.f?tv:0.2f*tv; m = fmaxf(m, tv); }
        #pragma unroll
        for (int off=1; off<64; off<<=1) m = fmaxf(m, __shfl_xor(m, off));
        float ss = 0.f;
        for (int i=lane; i<cnt; i+=64){ float tv = el[srcs[start+i]] + ern; tv = tv>=0.f?tv:0.2f*tv; ss += fexp2((tv-m)*LOG2E); }
        #pragma unroll
        for (int off=1; off<64; off<<=1) ss += __shfl_xor(ss, off);
        float inv = frcp(fmaxf(ss, 1e-16f));
        for (int i=slot; i<cnt; i+=4) {
            int sn = srcs[start+i];
            float tv = el[sn] + ern; tv = tv>=0.f?tv:0.2f*tv;
            float w0 = fexp2((tv-m)*LOG2E) * inv;
            short8 v0 = *(const short8*)(z + (size_t)sn*HH + ch);
            #pragma unroll
            for (int j=0;j<8;j++) acc[j] = fmaf(w0, b2f((u16)v0[j]), acc[j]);
        }
    }
    #pragma unroll
    for (int j=0;j<8;j++){ acc[j] += __shfl_xor(acc[j],16); acc[j] += __shfl_xor(acc[j],32); }
    if (slot == 0) {
        short8 o8;
        #pragma unroll
        for (int j=0;j<8;j++) o8[j] = (short)f2b(ftanh(acc[j] + bias[ch+j]));
        *(short8*)(hout + (size_t)n*HH + ch) = o8;
    }
}

extern "C" void kernel_launch(void* const* d_in, const int* in_sizes, int n_in,
                              void* d_out, int out_size, void* d_ws, size_t ws_size,
                              hipStream_t stream)
{
    const float* x    = (const float*)d_in[0];
    const int*   src  = (const int*)d_in[1];
    const int*   dst  = (const int*)d_in[2];
    const float* wxW  = (const float*)d_in[3];
    const float* wxb  = (const float*)d_in[4];
    const float* gatW = (const float*)d_in[5];
    const float* gatb = (const float*)d_in[6];
    const float* attl = (const float*)d_in[7];
    const float* attr = (const float*)d_in[8];
    const float* igW  = (const float*)d_in[9];
    const float* igb  = (const float*)d_in[10];
    const float* fgW  = (const float*)d_in[11];
    const float* fgb  = (const float*)d_in[12];
    const float* ogW  = (const float*)d_in[13];
    const float* ogb  = (const float*)d_in[14];
    const float* stW  = (const float*)d_in[15];
    const float* stb  = (const float*)d_in[16];
    const float* outW = (const float*)d_in[17];
    const float* outb = (const float*)d_in[18];

    char* w = (char*)d_ws;
    auto alloc = [&](size_t bytes)->char* { char* p = w; w += (bytes + 255) & ~(size_t)255; return p; };
    const size_t NH = (size_t)NN * HH;
    u16*      muB    = (u16*)alloc(NH*2);
    u16*      zB     = (u16*)alloc(NH*2);
    u16*      coll0  = (u16*)alloc(NH*2);
    u16*      coll1  = (u16*)alloc(NH*2);
    u16*      coll2  = (u16*)alloc(NH*2);
    float*    el     = (float*)alloc((size_t)NN*4);
    float*    er     = (float*)alloc((size_t)NN*4);
    unsigned* staged = (unsigned*)alloc((size_t)EE*4);
    u16*      srcs   = (u16*)alloc((size_t)EE*2);
    int*      deg    = (int*)alloc((size_t)NN*4);
    int*      rp     = (int*)alloc((size_t)NN*4);
    int*      bcnt   = (int*)alloc(128*4);
    int*      bbase  = (int*)alloc(128*4);
    int*      gcur   = (int*)alloc(128*4);
    u16*      bpool  = (u16*)alloc(483328*2);
    u16* wxP   = bpool;
    u16* gatP  = bpool + 32768;
    u16* gateP = bpool + 81920;
    u16* outP  = bpool + 475136;
    u16* coll[3] = {coll0, coll1, coll2};

    // ---- pack weights into MFMA fragment order ----
    PKs ps;
    ps.t[0] = {wxW, wxP, IN_D, HH};
    for (int i=0;i<3;i++) ps.t[1+i]  = {gatW + (size_t)i*HH*HH,   gatP  + i*16384,           HH,   HH};
    for (int i=0;i<3;i++) ps.t[4+i]  = {igW  + (size_t)i*2*HH*HH, gateP + i*131072,          2*HH, HH};
    for (int i=0;i<3;i++) ps.t[7+i]  = {stW  + (size_t)i*2*HH*HH, gateP + i*131072 + 32768,  2*HH, HH};
    for (int i=0;i<3;i++) ps.t[10+i] = {fgW  + (size_t)i*2*HH*HH, gateP + i*131072 + 65536,  2*HH, HH};
    for (int i=0;i<3;i++) ps.t[13+i] = {ogW  + (size_t)i*2*HH*HH, gateP + i*131072 + 98304,  2*HH, HH};
    ps.t[16] = {outW, outP, HH, OUT_D};
    pack_k<<<dim3(128,17), 256, 0, stream>>>(ps);

    // ---- bucketized CSR build ----
    hipMemsetAsync(bcnt, 0, 128*4, stream);
    const int gE = (EE + 4095) / 4096;   // 196
    binh_k <<<gE, 256, 0, stream>>>(dst, bcnt);
    bscan_k<<<1, 128, 0, stream>>>(bcnt, bbase, gcur);
    binsc_k<<<gE, 256, 0, stream>>>(dst, src, gcur, staged);
    build_k<<<NBK, BK, 0, stream>>>(bcnt, bbase, staged, rp, deg, srcs);

    const int gN = (NN + 63) / 64;   // 782
    const int gA = (NN + 3) / 4;     // 12500

    // ---- h0 = x @ wxW + wxb -> muB ----
    rgemm_k<EPI_BF,4,2,IN_D,float><<<gN, 256, 0, stream>>>(
        x, wxP, wxb, nullptr, muB, nullptr, nullptr, NN);

    // ---- GAT layers ----
    const u16* hin = muB;
    for (int i = 0; i < DEPTH; ++i) {
        rgemm_k<EPI_ZEL,4,2,HH,u16><<<gN, 256, 0, stream>>>(
            hin, gatP + i*16384, attl + i*HH, attr + i*HH, zB, el, er, NN);
        gat_k<<<gA, 256, 0, stream>>>(zB, el, er, srcs, rp, deg, gatb + i*HH, coll[i]);
        hin = coll[i];
    }

    // ---- depth + out: single fused kernel ----
    depth_k<<<gN, 512, 0, stream>>>(coll0, coll1, coll2, muB, gateP, outP,
                                    igb, stb, fgb, ogb, outb, (float*)d_out, NN);
}